// Round 15
// baseline (173.538 us; speedup 1.0000x reference)
//
#include <hip/hip_runtime.h>
#include <math.h>

#define QN 4096
#define NN 1024
#define FD 64
#define HD 128

typedef float v2f __attribute__((ext_vector_type(2)));
typedef float v4f __attribute__((ext_vector_type(4)));

// workspace layout (float offsets)
#define OFF_UT4   0                      // UT4 [32 h4][4096 q][4]
#define OFF_B     524288                 // B   [1024 n][128 h]
#define OFF_VU    655360                 // vu  [4096 q]
#define OFF_VB    659456                 // vb  [1024 n]
#define OFF_L     660480                 // L   [1024 n][4096 q]
#define OFF_PM    4854784                // pm  [64 tile][4096 q]
// end: 5116928 floats = 20.5 MB

// ---------------- K0: fused prep: UT4, B, vb, vu (R7 verbatim) ----------------
__global__ __launch_bounds__(256) void k0_prep(
    const float* __restrict__ qp, const float* __restrict__ nf,
    const float* __restrict__ npos, const float* __restrict__ aW1,
    const float* __restrict__ ab1, const float* __restrict__ aW2,
    float* __restrict__ B, float* __restrict__ UT4,
    float* __restrict__ vu, float* __restrict__ vb) {
  int bid = blockIdx.x, t = threadIdx.x;
  if (bid < 2048) {
    int idx = bid * 256 + t;
    int j = idx & 3, q = (idx >> 2) & 4095, h4 = idx >> 14;
    int h = h4 * 4 + j;
    float u = qp[q*3+0] * aW1[(FD+0)*HD + h]
            + qp[q*3+1] * aW1[(FD+1)*HD + h]
            + qp[q*3+2] * aW1[(FD+2)*HD + h];
    UT4[idx] = u;
  } else if (bid < 2560) {
    int i2 = (bid - 2048) * 256 + t;
    int n = i2 >> 7, h = i2 & 127;
    float s = ab1[h];
    #pragma unroll
    for (int f = 0; f < FD; ++f) s = fmaf(nf[n*FD+f], aW1[f*HD+h], s);
    s -= npos[n*3+0] * aW1[(FD+0)*HD + h]
       + npos[n*3+1] * aW1[(FD+1)*HD + h]
       + npos[n*3+2] * aW1[(FD+2)*HD + h];
    B[i2] = s;
    float pv = s * aW2[h];
    #pragma unroll
    for (int m = 1; m < 64; m <<= 1) pv += __shfl_xor(pv, m, 64);
    __shared__ float ps[4];
    if ((t & 63) == 0) ps[t >> 6] = pv;
    __syncthreads();
    if (t == 0)   vb[n] = ps[0] + ps[1];
    if (t == 128) vb[n] = ps[2] + ps[3];
  } else {
    int q = (bid - 2560) * 256 + t;
    float q0 = qp[q*3+0], q1 = qp[q*3+1], q2 = qp[q*3+2];
    float acc = 0.f;
    #pragma unroll
    for (int h = 0; h < HD; ++h) {
      float u = q0 * aW1[(FD+0)*HD + h]
              + q1 * aW1[(FD+1)*HD + h]
              + q2 * aW1[(FD+2)*HD + h];
      acc = fmaf(aW2[h], u, acc);
    }
    vu[q] = acc;
  }
}

// ---------------- K2: logits (R7 verbatim, measured 46.3 us) ----------------
#define LOADU(dst) { \
  _Pragma("unroll") for (int qq = 0; qq < 4; ++qq) { \
    dst[qq][0] = p0[qq*64]; \
    dst[qq][1] = p1[qq*64]; } \
  p0 += 8192; p1 += 8192; }

#define COMPUTE(u) { \
  _Pragma("unroll") for (int nn = 0; nn < 4; ++nn) { \
    v4f b0 = bsb[(nb + nn)*32]; \
    v4f b1 = bsb[(nb + nn)*32 + 1]; \
    v2f b01 = __builtin_shufflevector(b0, b0, 0, 1); \
    v2f b23 = __builtin_shufflevector(b0, b0, 2, 3); \
    v2f b45 = __builtin_shufflevector(b1, b1, 0, 1); \
    v2f b67 = __builtin_shufflevector(b1, b1, 2, 3); \
    _Pragma("unroll") for (int qq = 0; qq < 4; ++qq) { \
      v2f u01 = __builtin_shufflevector(u[qq][0], u[qq][0], 0, 1); \
      v2f u23 = __builtin_shufflevector(u[qq][0], u[qq][0], 2, 3); \
      v2f u45 = __builtin_shufflevector(u[qq][1], u[qq][1], 0, 1); \
      v2f u67 = __builtin_shufflevector(u[qq][1], u[qq][1], 2, 3); \
      v2f t0, t1, t2, t3; \
      asm("v_pk_add_f32 %0, %1, %2" : "=v"(t0) : "v"(u01), "v"(b01)); \
      asm("v_pk_add_f32 %0, %1, %2" : "=v"(t1) : "v"(u23), "v"(b23)); \
      asm("v_pk_add_f32 %0, %1, %2" : "=v"(t2) : "v"(u45), "v"(b45)); \
      asm("v_pk_add_f32 %0, %1, %2" : "=v"(t3) : "v"(u67), "v"(b67)); \
      float a = acc[qq][nn]; \
      a = fmaf(aw[0], __builtin_fabsf(t0.x), a); \
      a = fmaf(aw[1], __builtin_fabsf(t0.y), a); \
      a = fmaf(aw[2], __builtin_fabsf(t1.x), a); \
      a = fmaf(aw[3], __builtin_fabsf(t1.y), a); \
      a = fmaf(aw[4], __builtin_fabsf(t2.x), a); \
      a = fmaf(aw[5], __builtin_fabsf(t2.y), a); \
      a = fmaf(aw[6], __builtin_fabsf(t3.x), a); \
      a = fmaf(aw[7], __builtin_fabsf(t3.y), a); \
      acc[qq][nn] = a; } } \
  bsb += 2; aw += 8; }

__global__ __launch_bounds__(256) void k2_logits(
    const float* __restrict__ Bg, const float* __restrict__ UT4,
    const float* __restrict__ aW2, const float* __restrict__ ab2,
    const float* __restrict__ qp, const float* __restrict__ npos,
    const float* __restrict__ vu, const float* __restrict__ vb,
    float* __restrict__ L, float* __restrict__ pm) {
  __shared__ float Bs[16 * HD];      // 8 KB
  __shared__ float red[4][4][64];    // 4 KB
  const int q0 = blockIdx.x * 256, n0 = blockIdx.y * 16;
  const int t = threadIdx.x;
  {
    const float4* src = (const float4*)(Bg + n0 * HD);
    float4* dst = (float4*)Bs;
    #pragma unroll
    for (int r = 0; r < 2; ++r) dst[r*256 + t] = src[r*256 + t];
  }
  __syncthreads();
  const int lane = t & 63, w = t >> 6;
  const int nb = w * 4;

  float acc[4][4];
  #pragma unroll
  for (int qq = 0; qq < 4; ++qq)
    #pragma unroll
    for (int nn = 0; nn < 4; ++nn) acc[qq][nn] = 0.f;

  const v4f* p0 = (const v4f*)UT4 + q0 + lane;   // h4 even chunk
  const v4f* p1 = p0 + 4096;                     // h4 odd chunk
  const v4f* bsb = (const v4f*)Bs;
  const float* aw = aW2;

  v4f uA[4][2], uB4[4][2];
  LOADU(uA);
  #pragma unroll 1
  for (int hc = 0; hc < 14; hc += 2) {
    LOADU(uB4);
    COMPUTE(uA);
    LOADU(uA);
    COMPUTE(uB4);
  }
  LOADU(uB4);
  COMPUTE(uA);
  COMPUTE(uB4);

  const float bias2 = ab2[0];
  float qx[4], qy[4], vuq[4], m4[4];
  #pragma unroll
  for (int qq = 0; qq < 4; ++qq) {
    int q = q0 + qq*64 + lane;
    qx[qq] = qp[q*3+0];
    qy[qq] = qp[q*3+1];
    vuq[qq] = vu[q];
    m4[qq] = -3.4e38f;
  }
  #pragma unroll
  for (int nn = 0; nn < 4; ++nn) {
    int n = n0 + nb + nn;
    float px = npos[n*3+0], py = npos[n*3+1];
    float vbn = vb[n];
    #pragma unroll
    for (int qq = 0; qq < 4; ++qq) {
      float dx = qx[qq] - px, dy = qy[qq] - py;
      float wgt = 1.f / (sqrtf(dx*dx + dy*dy) + 1e-6f);
      float score = fmaf(0.5f, vuq[qq] + vbn + acc[qq][nn], bias2);
      float lg = score * wgt;
      L[n * QN + q0 + qq*64 + lane] = lg;
      m4[qq] = fmaxf(m4[qq], lg);
    }
  }
  #pragma unroll
  for (int qq = 0; qq < 4; ++qq) red[w][qq][lane] = m4[qq];
  __syncthreads();
  {
    int qq = t >> 6, ll = t & 63;
    float mm = fmaxf(fmaxf(red[0][qq][ll], red[1][qq][ll]),
                     fmaxf(red[2][qq][ll], red[3][qq][ll]));
    pm[blockIdx.y * QN + q0 + qq*64 + ll] = mm;
  }
}

// ---------------- KB: full-n aggregate + inline decode (no cross-block dep) --
// 512 blocks x 8 q. lane: qi=lane&7 (q), fh=lane>>3 (f-eighth).
// wave w covers n in [w*256,(w+1)*256). acc[8] f-slice per thread.
__global__ __launch_bounds__(256) void kB_aggdec(
    const float* __restrict__ L, const float* __restrict__ pm,
    const float* __restrict__ nf,
    const float* __restrict__ dW1, const float* __restrict__ db1,
    const float* __restrict__ dW2, const float* __restrict__ db2,
    float* __restrict__ out) {
  __shared__ float red[4][64][9];    // pad 9: conflict-free
  __shared__ float sred[4][64];
  __shared__ float agg[8][65];
  __shared__ float inv[8];
  __shared__ float h1s[8][128];
  const int t = threadIdx.x, lane = t & 63, w = t >> 6;
  const int qi = lane & 7, fh = lane >> 3;
  const int qb = blockIdx.x * 8;
  const int q = qb + qi;

  float m = -3.4e38f;
  #pragma unroll
  for (int k = 0; k < 64; ++k) m = fmaxf(m, pm[k * QN + q]);

  float acc[8];
  #pragma unroll
  for (int j = 0; j < 8; ++j) acc[j] = 0.f;
  float s = 0.f;

  const int n0w = w * 256;
  const float* Lp = L + (size_t)n0w * QN + q;
  const float4* nfp = (const float4*)(nf + n0w * FD + fh * 8);

  float pre[4];
  #pragma unroll
  for (int j = 0; j < 4; ++j) pre[j] = Lp[(size_t)j * QN];

  #pragma unroll 4
  for (int i = 0; i < 256; ++i) {
    float cur = pre[i & 3];
    if (i < 252) pre[i & 3] = Lp[(size_t)(i + 4) * QN];
    float p = exp2f((cur - m) * 1.44269504088896f);
    s += p;
    float4 a0 = nfp[i * 16];
    float4 a1 = nfp[i * 16 + 1];
    acc[0] = fmaf(p, a0.x, acc[0]);
    acc[1] = fmaf(p, a0.y, acc[1]);
    acc[2] = fmaf(p, a0.z, acc[2]);
    acc[3] = fmaf(p, a0.w, acc[3]);
    acc[4] = fmaf(p, a1.x, acc[4]);
    acc[5] = fmaf(p, a1.y, acc[5]);
    acc[6] = fmaf(p, a1.z, acc[6]);
    acc[7] = fmaf(p, a1.w, acc[7]);
  }

  #pragma unroll
  for (int j = 0; j < 8; ++j) red[w][lane][j] = acc[j];
  sred[w][lane] = s;
  __syncthreads();

  if (t < 64) {
    int tqi = t & 7, tfh = t >> 3;
    #pragma unroll
    for (int j = 0; j < 8; ++j) {
      float v = red[0][t][j] + red[1][t][j] + red[2][t][j] + red[3][t][j];
      agg[tqi][tfh * 8 + j] = v;
    }
  }
  if (t < 8) {
    float ssum = sred[0][t] + sred[1][t] + sred[2][t] + sred[3][t];
    inv[t] = 1.f / ssum;
  }
  __syncthreads();

  // decode stage 1: h1s[8][128]
  {
    int h = t & 127, qg = t >> 7;   // qg in [0,2)
    #pragma unroll
    for (int k = 0; k < 4; ++k) {
      int qs = qg * 4 + k;
      float a = 0.f;
      #pragma unroll
      for (int f = 0; f < 64; ++f) a = fmaf(agg[qs][f], dW1[f*HD + h], a);
      h1s[qs][h] = fmaxf(a * inv[qs] + db1[h], 0.f);
    }
  }
  __syncthreads();
  if (t < 24) {
    int qs = t / 3, o = t % 3;
    float a = db2[o];
    #pragma unroll
    for (int h = 0; h < HD; ++h) a = fmaf(h1s[qs][h], dW2[h*3 + o], a);
    out[(qb + qs)*3 + o] = a;
  }
}

extern "C" void kernel_launch(void* const* d_in, const int* in_sizes, int n_in,
                              void* d_out, int out_size, void* d_ws, size_t ws_size,
                              hipStream_t stream) {
  const float* qp   = (const float*)d_in[0];
  const float* nf   = (const float*)d_in[1];
  const float* npos = (const float*)d_in[2];
  const float* aW1  = (const float*)d_in[3];
  const float* ab1  = (const float*)d_in[4];
  const float* aW2  = (const float*)d_in[5];
  const float* ab2  = (const float*)d_in[6];
  const float* dW1  = (const float*)d_in[7];
  const float* db1  = (const float*)d_in[8];
  const float* dW2  = (const float*)d_in[9];
  const float* db2  = (const float*)d_in[10];

  float* ws    = (float*)d_ws;
  float* UT4   = ws + OFF_UT4;
  float* B     = ws + OFF_B;
  float* vu    = ws + OFF_VU;
  float* vb    = ws + OFF_VB;
  float* L     = ws + OFF_L;
  float* pm    = ws + OFF_PM;

  hipLaunchKernelGGL(k0_prep, dim3(2576), dim3(256), 0, stream,
                     qp, nf, npos, aW1, ab1, aW2, B, UT4, vu, vb);
  hipLaunchKernelGGL(k2_logits, dim3(16, 64), dim3(256), 0, stream,
                     B, UT4, aW2, ab2, qp, npos, vu, vb, L, pm);
  hipLaunchKernelGGL(kB_aggdec, dim3(512), dim3(256), 0, stream,
                     L, pm, nf, dW1, db1, dW2, db2, (float*)d_out);
}